// Round 10
// baseline (2409.490 us; speedup 1.0000x reference)
//
#include <hip/hip_runtime.h>
#include <math.h>

#define BB 256
#define TT 2048
#define HH 64

typedef _Float16 half2v __attribute__((ext_vector_type(2)));
typedef __fp16  fp16v2 __attribute__((ext_vector_type(2)));
union H2I { half2v h; int i; };

#if __has_builtin(__builtin_amdgcn_rcpf)
__device__ __forceinline__ float fast_rcp(float v) { return __builtin_amdgcn_rcpf(v); }
#else
__device__ __forceinline__ float fast_rcp(float v) { return 1.0f / v; }
#endif
#if __has_builtin(__builtin_amdgcn_rsqf)
__device__ __forceinline__ float fast_rsq(float v) { return __builtin_amdgcn_rsqf(v); }
#else
__device__ __forceinline__ float fast_rsq(float v) { return rsqrtf(v); }
#endif

__device__ __forceinline__ float tanh_fast(float v) {
    float e = __expf(2.0f * v);
    return fmaf(-2.0f, fast_rcp(e + 1.0f), 1.0f);
}
__device__ __forceinline__ float sigmoid_fast(float v) {
    return fast_rcp(1.0f + __expf(-v));
}
__device__ __forceinline__ float fdot2(half2v a, half2v b, float c) {
    return __builtin_amdgcn_fdot2(a, b, c, false);
}
__device__ __forceinline__ half2v pack_pair(float a, float b) {
    fp16v2 r = __builtin_amdgcn_cvt_pkrtz(a, b);
    return __builtin_bit_cast(half2v, r);
}
__device__ __forceinline__ void unpack_pair(int v, float& a, float& b) {
    H2I u; u.i = v;
    a = (float)u.h.x; b = (float)u.h.y;
}
__device__ __forceinline__ void pin_h2(half2v& v) {
    H2I u; u.h = v;
    asm volatile("" : "+v"(u.i));
    v = u.h;
}
__device__ __forceinline__ half2v bcast_pair(half2v v, int lane) {
    H2I u; u.h = v;
    H2I w; w.i = __builtin_amdgcn_readlane(u.i, lane);
    return w.h;
}
__device__ __forceinline__ float dpp_neighbor(float v) {
    return __int_as_float(__builtin_amdgcn_mov_dpp(__float_as_int(v), 0xB1, 0xf, 0xf, true));
}
template <int CTRL>
__device__ __forceinline__ float dpp_add_stage(float v) {
    int t = __builtin_amdgcn_update_dpp(0, __float_as_int(v), CTRL, 0xf, 0xf, true);
    return v + __int_as_float(t);
}
__device__ __forceinline__ float wave_sum_dpp(float v) {
    v = dpp_add_stage<0x111>(v);
    v = dpp_add_stage<0x112>(v);
    v = dpp_add_stage<0x114>(v);
    v = dpp_add_stage<0x118>(v);
    v = dpp_add_stage<0x142>(v);
    v = dpp_add_stage<0x143>(v);  // lane63 = total
    return v;
}

__global__ __launch_bounds__(512, 2)
void pgjanet_kernel(const float* __restrict__ x,
                    const float* __restrict__ h0,
                    const float* __restrict__ Wa,  const float* __restrict__ ba,
                    const float* __restrict__ Wp1, const float* __restrict__ bp1,
                    const float* __restrict__ Wp2, const float* __restrict__ bp2,
                    const float* __restrict__ Wf,  const float* __restrict__ bf,
                    const float* __restrict__ Wg,  const float* __restrict__ bg,
                    const float* __restrict__ Wo,  const float* __restrict__ bo,
                    float* __restrict__ out)
{
    const int tid = threadIdx.x;
    const int j   = tid & 63;                                    // hidden index
    const int w8  = __builtin_amdgcn_readfirstlane(tid >> 6);    // wave 0..7
    const int row = w8 >> 2;                                     // 0/1: which batch row
    const int w   = w8 & 3;                                      // role wave 0..3
    const int b   = 2 * blockIdx.x + row;                        // batch row

    __shared__ int   xs16[2][TT];        // 16 KB: packed f16 (xi,xq) pairs
    __shared__ float ybuf[2][TT * 2];    // 32 KB: output staging (2 rows, contiguous)
    __shared__ float exch[2][2][5][HH];  // 10 KB: [row][buf][gate][j]

    // ---- stage x as f16 pairs (each row staged by its own 4 waves) ----
    {
        const float2* xp2 = reinterpret_cast<const float2*>(x + (size_t)b * (TT * 2));
        const int lt = tid & 255;
        for (int i = lt; i < TT; i += 256) {
            float2 v = xp2[i];
            H2I u; u.h = pack_pair(v.x, v.y);
            xs16[row][i] = u.i;
        }
    }

    // ---- per-wave weight assignment (same for both rows) ----
    // wave0: a-gate, wave1: p1-gate, wave2: p2-gate, wave3: f_h + g_h
    const float* gsrc  = (w == 0) ? Wa : (w == 1) ? Wp1 : (w == 2) ? Wp2 : Wf;
    const int    gld   = (w < 3) ? (HH + 1) : (2 * HH);
    const float* g2src = (w == 3) ? Wg : gsrc;
    const int    g2ld  = (w == 3) ? (2 * HH) : gld;

    half2v wgate[32], wgate2[32], wfuv[32], wguv[32];
#pragma unroll
    for (int m = 0; m < 32; ++m) {
        wgate[m]  = pack_pair(gsrc [j * gld  + 2 * m], gsrc [j * gld  + 2 * m + 1]);
        wgate2[m] = pack_pair(g2src[j * g2ld + 2 * m], g2src[j * g2ld + 2 * m + 1]);
        wfuv[m]   = pack_pair(Wf[j * (2 * HH) + HH + 2 * m], Wf[j * (2 * HH) + HH + 2 * m + 1]);
        wguv[m]   = pack_pair(Wg[j * (2 * HH) + HH + 2 * m], Wg[j * (2 * HH) + HH + 2 * m + 1]);
    }
#pragma unroll
    for (int m = 0; m < 32; ++m) {
        pin_h2(wgate[m]); pin_h2(wgate2[m]); pin_h2(wfuv[m]); pin_h2(wguv[m]);
    }

    const float xw   = (w == 0) ? Wa [j * (HH + 1) + HH]
                     : (w == 1) ? Wp1[j * (HH + 1) + HH]
                     : (w == 2) ? Wp2[j * (HH + 1) + HH] : 0.f;
    const float bsel = (w == 0) ? ba[j] : (w == 1) ? bp1[j] : (w == 2) ? bp2[j] : 0.f;
    const float bf_r = bf[j], bg_r = bg[j];
    const float wo0 = Wo[j], wo1 = Wo[HH + j];
    const float bo0 = bo[0], bo1 = bo[1];

    float h = h0[b * HH + j];

    __syncthreads();   // xs16 ready

    // x-scalar pipeline, selected per wave role
    float xsel;
    {
        float xi, xq; unpack_pair(xs16[row][0], xi, xq);
        float r2 = xi * xi + xq * xq;
        float rsq = fast_rsq(r2);
        bool ok = r2 > 0.f;
        float amp = ok ? r2 * rsq : 0.f;
        float ct  = ok ? xi * rsq : 1.f;
        float st  = ok ? xq * rsq : 0.f;
        xsel = (w == 0) ? amp : (w == 1) ? ct : st;
    }

    for (int t = 0; t < TT; ++t) {
        float (*ex)[HH] = exch[row][t & 1];

        // next step's x scalars (off the critical path)
        const int tn = (t + 1 < TT) ? (t + 1) : (TT - 1);
        float xsel_n;
        {
            float xi_n, xq_n; unpack_pair(xs16[row][tn], xi_n, xq_n);
            float r2 = xi_n * xi_n + xq_n * xq_n;
            float rsq = fast_rsq(r2);
            bool ok = r2 > 0.f;
            float amp = ok ? r2 * rsq : 0.f;
            float ct  = ok ? xi_n * rsq : 1.f;
            float st  = ok ? xq_n * rsq : 0.f;
            xsel_n = (w == 0) ? amp : (w == 1) ? ct : st;
        }

        // broadcast all 32 h pairs
        float hnbr = dpp_neighbor(h);
        half2v hp = pack_pair(h, hnbr);
        half2v sh[32];
#pragma unroll
        for (int m = 0; m < 32; ++m) sh[m] = bcast_pair(hp, 2 * m);

        // ---- phase A (gate-split): 32 dot2, 4 accumulators ----
        float a0 = 0.f, a1 = 0.f, a2 = 0.f, a3 = 0.f;
#pragma unroll
        for (int m = 0; m < 8; ++m) {
            a0 = fdot2(sh[m],      wgate[m],      a0);
            a1 = fdot2(sh[m + 8],  wgate[m + 8],  a1);
            a2 = fdot2(sh[m + 16], wgate[m + 16], a2);
            a3 = fdot2(sh[m + 24], wgate[m + 24], a3);
        }
        float pre = (a0 + a1) + (a2 + a3);

        if (w == 3) {
            float b0 = 0.f, b1 = 0.f, b2 = 0.f, b3 = 0.f;
#pragma unroll
            for (int m = 0; m < 8; ++m) {
                b0 = fdot2(sh[m],      wgate2[m],      b0);
                b1 = fdot2(sh[m + 8],  wgate2[m + 8],  b1);
                b2 = fdot2(sh[m + 16], wgate2[m + 16], b2);
                b3 = fdot2(sh[m + 24], wgate2[m + 24], b3);
            }
            ex[3][j] = pre + bf_r;                      // f_h + bf
            ex[4][j] = ((b0 + b1) + (b2 + b3)) + bg_r;  // g_h + bg
        } else {
            ex[w][j] = tanh_fast(pre + fmaf(xsel, xw, bsel));
        }

        __syncthreads();   // single barrier per step (syncs both rows)

        float av  = ex[0][j];
        float pv1 = ex[1][j];
        float pv2 = ex[2][j];
        float fh  = ex[3][j];
        float gh  = ex[4][j];
        float u = (av * (1.f - av)) * (pv1 * (1.f - pv1)) * (pv2 * (1.f - pv2));

        // broadcast all 32 u pairs
        float unbr = dpp_neighbor(u);
        half2v upk = pack_pair(u, unbr);
        half2v su[32];
#pragma unroll
        for (int m = 0; m < 32; ++m) su[m] = bcast_pair(upk, 2 * m);

        // ---- phase C replicated: f,g u-parts (64 dot2, 8 chains) ----
        float f0 = 0.f, f1 = 0.f, f2 = 0.f, f3 = 0.f;
        float g0 = 0.f, g1 = 0.f, g2 = 0.f, g3 = 0.f;
#pragma unroll
        for (int m = 0; m < 8; ++m) {
            f0 = fdot2(su[m],      wfuv[m],      f0);
            f1 = fdot2(su[m + 8],  wfuv[m + 8],  f1);
            f2 = fdot2(su[m + 16], wfuv[m + 16], f2);
            f3 = fdot2(su[m + 24], wfuv[m + 24], f3);
            g0 = fdot2(su[m],      wguv[m],      g0);
            g1 = fdot2(su[m + 8],  wguv[m + 8],  g1);
            g2 = fdot2(su[m + 16], wguv[m + 16], g2);
            g3 = fdot2(su[m + 24], wguv[m + 24], g3);
        }
        float f = sigmoid_fast(fh + (f0 + f1) + (f2 + f3));
        float g = tanh_fast(gh + (g0 + g1) + (g2 + g3));
        h = fmaf(f, h - g, g);   // f*h + (1-f)*g  (identical in the row's 4 waves)

        // y_t — rotating wave within each row, DPP reduce, LDS-buffered
        if (w == (t & 3)) {
            float y0 = wave_sum_dpp(h * wo0);
            float y1 = wave_sum_dpp(h * wo1);
            if (j == 63) {
                ybuf[row][2 * t]     = y0 + bo0;
                ybuf[row][2 * t + 1] = y1 + bo1;
            }
        }

        xsel = xsel_n;
    }

    // ---- flush y to global: 2 rows contiguous, coalesced float4 ----
    __syncthreads();
    {
        const float4* ys4 = reinterpret_cast<const float4*>(&ybuf[0][0]);
        float4*       yp4 = reinterpret_cast<float4*>(out + (size_t)(2 * blockIdx.x) * (TT * 2));
        for (int i = tid; i < TT; i += 512) yp4[i] = ys4[i];   // 2*TT*2/4 = TT float4s
    }
}

extern "C" void kernel_launch(void* const* d_in, const int* in_sizes, int n_in,
                              void* d_out, int out_size, void* d_ws, size_t ws_size,
                              hipStream_t stream) {
    const float* x   = (const float*)d_in[0];
    const float* h0  = (const float*)d_in[1];
    const float* Wa  = (const float*)d_in[2];
    const float* ba  = (const float*)d_in[3];
    const float* Wp1 = (const float*)d_in[4];
    const float* bp1 = (const float*)d_in[5];
    const float* Wp2 = (const float*)d_in[6];
    const float* bp2 = (const float*)d_in[7];
    const float* Wf  = (const float*)d_in[8];
    const float* bf  = (const float*)d_in[9];
    const float* Wg  = (const float*)d_in[10];
    const float* bg  = (const float*)d_in[11];
    const float* Wo  = (const float*)d_in[12];
    const float* bo  = (const float*)d_in[13];
    float* out = (float*)d_out;

    pgjanet_kernel<<<dim3(BB / 2), dim3(512), 0, stream>>>(
        x, h0, Wa, ba, Wp1, bp1, Wp2, bp2, Wf, bf, Wg, bg, Wo, bo, out);
}

// Round 11
// 1781.483 us; speedup vs baseline: 1.3525x; 1.3525x over previous
//
#include <hip/hip_runtime.h>
#include <math.h>

#define BB 256
#define TT 2048
#define HH 64

typedef _Float16 half2v __attribute__((ext_vector_type(2)));
typedef __fp16  fp16v2 __attribute__((ext_vector_type(2)));
union H2I { half2v h; int i; };

#if __has_builtin(__builtin_amdgcn_rcpf)
__device__ __forceinline__ float fast_rcp(float v) { return __builtin_amdgcn_rcpf(v); }
#else
__device__ __forceinline__ float fast_rcp(float v) { return 1.0f / v; }
#endif
#if __has_builtin(__builtin_amdgcn_rsqf)
__device__ __forceinline__ float fast_rsq(float v) { return __builtin_amdgcn_rsqf(v); }
#else
__device__ __forceinline__ float fast_rsq(float v) { return rsqrtf(v); }
#endif

__device__ __forceinline__ float tanh_fast(float v) {
    float e = __expf(2.0f * v);
    return fmaf(-2.0f, fast_rcp(e + 1.0f), 1.0f);
}
__device__ __forceinline__ float sigmoid_fast(float v) {
    return fast_rcp(1.0f + __expf(-v));
}
__device__ __forceinline__ float fdot2(half2v a, half2v b, float c) {
    return __builtin_amdgcn_fdot2(a, b, c, false);
}
__device__ __forceinline__ half2v pack_pair(float a, float b) {
    fp16v2 r = __builtin_amdgcn_cvt_pkrtz(a, b);
    return __builtin_bit_cast(half2v, r);
}
__device__ __forceinline__ void unpack_pair(int v, float& a, float& b) {
    H2I u; u.i = v;
    a = (float)u.h.x; b = (float)u.h.y;
}
__device__ __forceinline__ void pin_h2(half2v& v) {
    H2I u; u.h = v;
    asm volatile("" : "+v"(u.i));
    v = u.h;
}
__device__ __forceinline__ half2v bcast_pair(half2v v, int lane) {
    H2I u; u.h = v;
    H2I w; w.i = __builtin_amdgcn_readlane(u.i, lane);
    return w.h;
}
__device__ __forceinline__ float dpp_neighbor(float v) {
    return __int_as_float(__builtin_amdgcn_mov_dpp(__float_as_int(v), 0xB1, 0xf, 0xf, true));
}
template <int CTRL>
__device__ __forceinline__ float dpp_add_stage(float v) {
    int t = __builtin_amdgcn_update_dpp(0, __float_as_int(v), CTRL, 0xf, 0xf, true);
    return v + __int_as_float(t);
}
__device__ __forceinline__ float wave_sum_dpp(float v) {
    v = dpp_add_stage<0x111>(v);
    v = dpp_add_stage<0x112>(v);
    v = dpp_add_stage<0x114>(v);
    v = dpp_add_stage<0x118>(v);
    v = dpp_add_stage<0x142>(v);
    v = dpp_add_stage<0x143>(v);  // lane63 = total
    return v;
}

__global__ __launch_bounds__(256, 1)
void pgjanet_kernel(const float* __restrict__ x,
                    const float* __restrict__ h0,
                    const float* __restrict__ Wa,  const float* __restrict__ ba,
                    const float* __restrict__ Wp1, const float* __restrict__ bp1,
                    const float* __restrict__ Wp2, const float* __restrict__ bp2,
                    const float* __restrict__ Wf,  const float* __restrict__ bf,
                    const float* __restrict__ Wg,  const float* __restrict__ bg,
                    const float* __restrict__ Wo,  const float* __restrict__ bo,
                    float* __restrict__ out)
{
    const int b   = blockIdx.x;
    const int tid = threadIdx.x;
    const int j   = tid & 63;
    const int w   = __builtin_amdgcn_readfirstlane(tid >> 6);   // wave 0..3

    __shared__ int   xs16[TT];        // 8 KB packed f16 (xi,xq)
    __shared__ float ybuf[TT * 2];    // 16 KB output staging
    __shared__ float exch[2][8][HH];  // 4 KB: e_a,e_p1,e_p2,fh, g0..g3

    // ---- stage x as f16 pairs ----
    {
        const float2* xp2 = reinterpret_cast<const float2*>(x + (size_t)b * (TT * 2));
        for (int i = tid; i < TT; i += 256) {
            float2 v = xp2[i];
            H2I u; u.h = pack_pair(v.x, v.y);
            xs16[i] = u.i;
        }
    }

    // ---- per-wave weights ----
    // wave0: a, wave1: p1, wave2: p2, wave3: f_h ; g_h split 4-way by k-slice
    const float* gsrc = (w == 0) ? Wa : (w == 1) ? Wp1 : (w == 2) ? Wp2 : Wf;
    const int    gld  = (w < 3) ? (HH + 1) : (2 * HH);

    half2v wgate[32], wgsl[8], wfuv[32], wguv[32];
#pragma unroll
    for (int m = 0; m < 32; ++m) {
        wgate[m] = pack_pair(gsrc[j * gld + 2 * m], gsrc[j * gld + 2 * m + 1]);
        wfuv[m]  = pack_pair(Wf[j * (2 * HH) + HH + 2 * m], Wf[j * (2 * HH) + HH + 2 * m + 1]);
        wguv[m]  = pack_pair(Wg[j * (2 * HH) + HH + 2 * m], Wg[j * (2 * HH) + HH + 2 * m + 1]);
    }
#pragma unroll
    for (int m = 0; m < 8; ++m) {
        const int k = 16 * w + 2 * m;
        wgsl[m] = pack_pair(Wg[j * (2 * HH) + k], Wg[j * (2 * HH) + k + 1]);
    }
#pragma unroll
    for (int m = 0; m < 32; ++m) { pin_h2(wgate[m]); pin_h2(wfuv[m]); pin_h2(wguv[m]); }
#pragma unroll
    for (int m = 0; m < 8; ++m)  { pin_h2(wgsl[m]); }

    const float xw   = (w == 0) ? Wa [j * (HH + 1) + HH]
                     : (w == 1) ? Wp1[j * (HH + 1) + HH]
                     : (w == 2) ? Wp2[j * (HH + 1) + HH] : 0.f;
    const float bsel = (w == 0) ? ba[j] : (w == 1) ? bp1[j] : (w == 2) ? bp2[j] : 0.f;
    const float bf_r = bf[j], bg_r = bg[j];
    const float wo0 = Wo[j], wo1 = Wo[HH + j];
    const float bo0 = bo[0], bo1 = bo[1];

    float h = h0[b * HH + j];
    float* yp = out + (size_t)b * (TT * 2);

    __syncthreads();   // xs16 ready

    // role-specific x scalar
    float xsel = 0.f;
    if (w < 3) {
        float xi, xq; unpack_pair(xs16[0], xi, xq);
        float r2 = xi * xi + xq * xq;
        float rsq = fast_rsq(r2);
        bool ok = r2 > 0.f;
        xsel = (w == 0) ? (ok ? r2 * rsq : 0.f)
             : (w == 1) ? (ok ? xi * rsq : 1.f)
             :            (ok ? xq * rsq : 0.f);
    }

    for (int t = 0; t < TT; ++t) {
        float (*ex)[HH] = exch[t & 1];

        // next step's x scalar (off critical path)
        const int tn = (t + 1 < TT) ? (t + 1) : (TT - 1);
        float xsel_n = 0.f;
        if (w < 3) {
            float xi, xq; unpack_pair(xs16[tn], xi, xq);
            float r2 = xi * xi + xq * xq;
            float rsq = fast_rsq(r2);
            bool ok = r2 > 0.f;
            xsel_n = (w == 0) ? (ok ? r2 * rsq : 0.f)
                   : (w == 1) ? (ok ? xi * rsq : 1.f)
                   :            (ok ? xq * rsq : 0.f);
        }

        // broadcast all 32 h pairs
        float hnbr = dpp_neighbor(h);
        half2v hp = pack_pair(h, hnbr);
        half2v sh[32];
#pragma unroll
        for (int m = 0; m < 32; ++m) sh[m] = bcast_pair(hp, 2 * m);

        // ---- phase A: gate dots (32) ----
        float a0 = 0.f, a1 = 0.f, a2 = 0.f, a3 = 0.f;
#pragma unroll
        for (int m = 0; m < 8; ++m) {
            a0 = fdot2(sh[m],      wgate[m],      a0);
            a1 = fdot2(sh[m + 8],  wgate[m + 8],  a1);
            a2 = fdot2(sh[m + 16], wgate[m + 16], a2);
            a3 = fdot2(sh[m + 24], wgate[m + 24], a3);
        }
        float pre = (a0 + a1) + (a2 + a3);

        // ---- g-slice dots (8) — compile-time sh indices per wave arm ----
        float gs0 = 0.f, gs1 = 0.f;
        if (w == 0) {
#pragma unroll
            for (int m = 0; m < 4; ++m) { gs0 = fdot2(sh[m], wgsl[m], gs0); gs1 = fdot2(sh[m + 4], wgsl[m + 4], gs1); }
        } else if (w == 1) {
#pragma unroll
            for (int m = 0; m < 4; ++m) { gs0 = fdot2(sh[8 + m], wgsl[m], gs0); gs1 = fdot2(sh[12 + m], wgsl[m + 4], gs1); }
        } else if (w == 2) {
#pragma unroll
            for (int m = 0; m < 4; ++m) { gs0 = fdot2(sh[16 + m], wgsl[m], gs0); gs1 = fdot2(sh[20 + m], wgsl[m + 4], gs1); }
        } else {
#pragma unroll
            for (int m = 0; m < 4; ++m) { gs0 = fdot2(sh[24 + m], wgsl[m], gs0); gs1 = fdot2(sh[28 + m], wgsl[m + 4], gs1); }
        }

        if (w == 3) {
            ex[3][j] = pre + bf_r;               // f_h + bf
        } else {
            float s = tanh_fast(pre + fmaf(xsel, xw, bsel));
            ex[w][j] = s * (1.f - s);            // store s(1-s): u = e0*e1*e2
        }
        ex[4 + w][j] = gs0 + gs1;                // g_h partial

        __syncthreads();   // single barrier per step

        float e0 = ex[0][j], e1 = ex[1][j], e2 = ex[2][j];
        float fh = ex[3][j];
        float gh = (ex[4][j] + ex[5][j]) + (ex[6][j] + ex[7][j]);
        float u = (e0 * e1) * e2;

        // broadcast all 32 u pairs
        float unbr = dpp_neighbor(u);
        half2v upk = pack_pair(u, unbr);
        half2v su[32];
#pragma unroll
        for (int m = 0; m < 32; ++m) su[m] = bcast_pair(upk, 2 * m);

        // ---- phase C replicated: f,g u-parts (64 dot2, 8 chains) ----
        float f0 = 0.f, f1 = 0.f, f2 = 0.f, f3 = 0.f;
        float g0 = 0.f, g1 = 0.f, g2 = 0.f, g3 = 0.f;
#pragma unroll
        for (int m = 0; m < 8; ++m) {
            f0 = fdot2(su[m],      wfuv[m],      f0);
            f1 = fdot2(su[m + 8],  wfuv[m + 8],  f1);
            f2 = fdot2(su[m + 16], wfuv[m + 16], f2);
            f3 = fdot2(su[m + 24], wfuv[m + 24], f3);
            g0 = fdot2(su[m],      wguv[m],      g0);
            g1 = fdot2(su[m + 8],  wguv[m + 8],  g1);
            g2 = fdot2(su[m + 16], wguv[m + 16], g2);
            g3 = fdot2(su[m + 24], wguv[m + 24], g3);
        }
        float f = sigmoid_fast(fh + (f0 + f1) + (f2 + f3));
        float g = tanh_fast(gh + bg_r + (g0 + g1) + (g2 + g3));
        h = fmaf(f, h - g, g);   // f*h + (1-f)*g

        // y_t — rotating wave, DPP reduce, LDS-buffered
        if (w == (t & 3)) {
            float y0 = wave_sum_dpp(h * wo0);
            float y1 = wave_sum_dpp(h * wo1);
            if (j == 63) {
                ybuf[2 * t]     = y0 + bo0;
                ybuf[2 * t + 1] = y1 + bo1;
            }
        }

        xsel = xsel_n;
    }

    // ---- flush y to global, coalesced float4 ----
    __syncthreads();
    {
        const float4* ys4 = reinterpret_cast<const float4*>(ybuf);
        float4*       yp4 = reinterpret_cast<float4*>(yp);
        for (int i = tid; i < TT * 2 / 4; i += 256) yp4[i] = ys4[i];
    }
}

extern "C" void kernel_launch(void* const* d_in, const int* in_sizes, int n_in,
                              void* d_out, int out_size, void* d_ws, size_t ws_size,
                              hipStream_t stream) {
    const float* x   = (const float*)d_in[0];
    const float* h0  = (const float*)d_in[1];
    const float* Wa  = (const float*)d_in[2];
    const float* ba  = (const float*)d_in[3];
    const float* Wp1 = (const float*)d_in[4];
    const float* bp1 = (const float*)d_in[5];
    const float* Wp2 = (const float*)d_in[6];
    const float* bp2 = (const float*)d_in[7];
    const float* Wf  = (const float*)d_in[8];
    const float* bf  = (const float*)d_in[9];
    const float* Wg  = (const float*)d_in[10];
    const float* bg  = (const float*)d_in[11];
    const float* Wo  = (const float*)d_in[12];
    const float* bo  = (const float*)d_in[13];
    float* out = (float*)d_out;

    pgjanet_kernel<<<dim3(BB), dim3(256), 0, stream>>>(
        x, h0, Wa, ba, Wp1, bp1, Wp2, bp2, Wf, bf, Wg, bg, Wo, bo, out);
}

// Round 12
// 1557.702 us; speedup vs baseline: 1.5468x; 1.1437x over previous
//
#include <hip/hip_runtime.h>
#include <math.h>

#define BB 256
#define TT 2048
#define HH 64

typedef _Float16 half2v __attribute__((ext_vector_type(2)));
typedef __fp16  fp16v2 __attribute__((ext_vector_type(2)));
union H2I { half2v h; int i; };

#if __has_builtin(__builtin_amdgcn_rcpf)
__device__ __forceinline__ float fast_rcp(float v) { return __builtin_amdgcn_rcpf(v); }
#else
__device__ __forceinline__ float fast_rcp(float v) { return 1.0f / v; }
#endif
#if __has_builtin(__builtin_amdgcn_rsqf)
__device__ __forceinline__ float fast_rsq(float v) { return __builtin_amdgcn_rsqf(v); }
#else
__device__ __forceinline__ float fast_rsq(float v) { return rsqrtf(v); }
#endif

__device__ __forceinline__ float tanh_fast(float v) {
    float e = __expf(2.0f * v);
    return fmaf(-2.0f, fast_rcp(e + 1.0f), 1.0f);
}
__device__ __forceinline__ float sigmoid_fast(float v) {
    return fast_rcp(1.0f + __expf(-v));
}
__device__ __forceinline__ float fdot2(half2v a, half2v b, float c) {
    return __builtin_amdgcn_fdot2(a, b, c, false);
}
__device__ __forceinline__ half2v pack_pair(float a, float b) {
    fp16v2 r = __builtin_amdgcn_cvt_pkrtz(a, b);
    return __builtin_bit_cast(half2v, r);
}
__device__ __forceinline__ void unpack_pair(int v, float& a, float& b) {
    H2I u; u.i = v;
    a = (float)u.h.x; b = (float)u.h.y;
}
__device__ __forceinline__ void pin_h2(half2v& v) {
    H2I u; u.h = v;
    asm volatile("" : "+v"(u.i));
    v = u.h;
}
// broadcast packed f16x2 from lane (lane may be an SGPR-uniform expression)
__device__ __forceinline__ half2v bcast_pair(half2v v, int lane) {
    H2I u; u.h = v;
    H2I w; w.i = __builtin_amdgcn_readlane(u.i, lane);
    return w.h;
}
__device__ __forceinline__ float dpp_neighbor(float v) {
    return __int_as_float(__builtin_amdgcn_mov_dpp(__float_as_int(v), 0xB1, 0xf, 0xf, true));
}
template <int CTRL>
__device__ __forceinline__ float dpp_add_stage(float v) {
    int t = __builtin_amdgcn_update_dpp(0, __float_as_int(v), CTRL, 0xf, 0xf, true);
    return v + __int_as_float(t);
}
__device__ __forceinline__ float wave_sum_dpp(float v) {
    v = dpp_add_stage<0x111>(v);
    v = dpp_add_stage<0x112>(v);
    v = dpp_add_stage<0x114>(v);
    v = dpp_add_stage<0x118>(v);
    v = dpp_add_stage<0x142>(v);
    v = dpp_add_stage<0x143>(v);  // lane63 = total
    return v;
}

__global__ __launch_bounds__(256, 1)
void pgjanet_kernel(const float* __restrict__ x,
                    const float* __restrict__ h0,
                    const float* __restrict__ Wa,  const float* __restrict__ ba,
                    const float* __restrict__ Wp1, const float* __restrict__ bp1,
                    const float* __restrict__ Wp2, const float* __restrict__ bp2,
                    const float* __restrict__ Wf,  const float* __restrict__ bf,
                    const float* __restrict__ Wg,  const float* __restrict__ bg,
                    const float* __restrict__ Wo,  const float* __restrict__ bo,
                    float* __restrict__ out)
{
    const int b   = blockIdx.x;
    const int tid = threadIdx.x;
    const int j   = tid & 63;
    const int w   = __builtin_amdgcn_readfirstlane(tid >> 6);   // wave 0..3
    const int gk  = 16 * w;                                     // g-slice base (uniform)

    __shared__ int   xs16[TT];        // 8 KB packed f16 (xi,xq)
    __shared__ float ybuf[TT * 2];    // 16 KB output staging
    __shared__ float exch[2][8][HH];  // 4 KB: e_a,e_p1,e_p2,fh, g0..g3

    // ---- stage x as f16 pairs ----
    {
        const float2* xp2 = reinterpret_cast<const float2*>(x + (size_t)b * (TT * 2));
        for (int i = tid; i < TT; i += 256) {
            float2 v = xp2[i];
            H2I u; u.h = pack_pair(v.x, v.y);
            xs16[i] = u.i;
        }
    }

    // ---- per-wave weights (branchless role selection) ----
    // wave0: a, wave1: p1, wave2: p2, wave3: f_h ; g_h split 4-way by k-slice
    const float* gsrc = (w == 0) ? Wa : (w == 1) ? Wp1 : (w == 2) ? Wp2 : Wf;
    const int    gld  = (w < 3) ? (HH + 1) : (2 * HH);

    half2v wgate[32], wgsl[8], wfuv[32], wguv[32];
#pragma unroll
    for (int m = 0; m < 32; ++m) {
        wgate[m] = pack_pair(gsrc[j * gld + 2 * m], gsrc[j * gld + 2 * m + 1]);
        wfuv[m]  = pack_pair(Wf[j * (2 * HH) + HH + 2 * m], Wf[j * (2 * HH) + HH + 2 * m + 1]);
        wguv[m]  = pack_pair(Wg[j * (2 * HH) + HH + 2 * m], Wg[j * (2 * HH) + HH + 2 * m + 1]);
    }
#pragma unroll
    for (int m = 0; m < 8; ++m) {
        wgsl[m] = pack_pair(Wg[j * (2 * HH) + gk + 2 * m], Wg[j * (2 * HH) + gk + 2 * m + 1]);
    }
#pragma unroll
    for (int m = 0; m < 32; ++m) { pin_h2(wgate[m]); pin_h2(wfuv[m]); pin_h2(wguv[m]); }
#pragma unroll
    for (int m = 0; m < 8; ++m)  { pin_h2(wgsl[m]); }

    const float xw   = (w == 0) ? Wa [j * (HH + 1) + HH]
                     : (w == 1) ? Wp1[j * (HH + 1) + HH]
                     : (w == 2) ? Wp2[j * (HH + 1) + HH] : 0.f;
    const float bsel = (w == 0) ? ba[j] : (w == 1) ? bp1[j] : (w == 2) ? bp2[j] : 0.f;
    const float bf_r = bf[j], bg_r = bg[j];
    const float wo0 = Wo[j], wo1 = Wo[HH + j];
    const float bo0 = bo[0], bo1 = bo[1];

    float h = h0[b * HH + j];
    float* yp = out + (size_t)b * (TT * 2);

    __syncthreads();   // xs16 ready

    // branchless x scalar per role (as R9)
    float xsel;
    {
        float xi, xq; unpack_pair(xs16[0], xi, xq);
        float r2 = xi * xi + xq * xq;
        float rsq = fast_rsq(r2);
        bool ok = r2 > 0.f;
        float amp = ok ? r2 * rsq : 0.f;
        float ct  = ok ? xi * rsq : 1.f;
        float st  = ok ? xq * rsq : 0.f;
        xsel = (w == 0) ? amp : (w == 1) ? ct : st;
    }

    for (int t = 0; t < TT; ++t) {
        float (*ex)[HH] = exch[t & 1];

        // next step's x scalar (off critical path)
        const int tn = (t + 1 < TT) ? (t + 1) : (TT - 1);
        float xsel_n;
        {
            float xi, xq; unpack_pair(xs16[tn], xi, xq);
            float r2 = xi * xi + xq * xq;
            float rsq = fast_rsq(r2);
            bool ok = r2 > 0.f;
            float amp = ok ? r2 * rsq : 0.f;
            float ct  = ok ? xi * rsq : 1.f;
            float st  = ok ? xq * rsq : 0.f;
            xsel_n = (w == 0) ? amp : (w == 1) ? ct : st;
        }

        // broadcast all 32 h pairs (+ this wave's 8 g-slice pairs, SGPR offset)
        float hnbr = dpp_neighbor(h);
        half2v hp = pack_pair(h, hnbr);
        half2v sh[32];
#pragma unroll
        for (int m = 0; m < 32; ++m) sh[m] = bcast_pair(hp, 2 * m);

        // ---- phase A: gate dots (32, 4 chains) ----
        float a0 = 0.f, a1 = 0.f, a2 = 0.f, a3 = 0.f;
#pragma unroll
        for (int m = 0; m < 8; ++m) {
            a0 = fdot2(sh[m],      wgate[m],      a0);
            a1 = fdot2(sh[m + 8],  wgate[m + 8],  a1);
            a2 = fdot2(sh[m + 16], wgate[m + 16], a2);
            a3 = fdot2(sh[m + 24], wgate[m + 24], a3);
        }
        float pre = (a0 + a1) + (a2 + a3);

        // ---- g_h slice: 8 dots, branchless (readlane at SGPR offset gk) ----
        float gs0 = 0.f, gs1 = 0.f;
#pragma unroll
        for (int m = 0; m < 4; ++m) {
            gs0 = fdot2(bcast_pair(hp, gk + 2 * m),     wgsl[m],     gs0);
            gs1 = fdot2(bcast_pair(hp, gk + 2 * m + 8), wgsl[m + 4], gs1);
        }
        ex[4 + w][j] = gs0 + gs1;   // g_h partial

        if (w == 3) {
            ex[3][j] = pre + bf_r;                       // f_h + bf
        } else {
            float s = tanh_fast(pre + fmaf(xsel, xw, bsel));
            ex[w][j] = s * (1.f - s);                    // u = e0*e1*e2
        }

        __syncthreads();   // single barrier per step

        float e0 = ex[0][j], e1 = ex[1][j], e2 = ex[2][j];
        float fh = ex[3][j];
        float gh = (ex[4][j] + ex[5][j]) + (ex[6][j] + ex[7][j]);
        float u = (e0 * e1) * e2;

        // broadcast all 32 u pairs
        float unbr = dpp_neighbor(u);
        half2v upk = pack_pair(u, unbr);
        half2v su[32];
#pragma unroll
        for (int m = 0; m < 32; ++m) su[m] = bcast_pair(upk, 2 * m);

        // ---- phase C replicated: f,g u-parts (64 dot2, 8 chains) ----
        float f0 = 0.f, f1 = 0.f, f2 = 0.f, f3 = 0.f;
        float g0 = 0.f, g1 = 0.f, g2 = 0.f, g3 = 0.f;
#pragma unroll
        for (int m = 0; m < 8; ++m) {
            f0 = fdot2(su[m],      wfuv[m],      f0);
            f1 = fdot2(su[m + 8],  wfuv[m + 8],  f1);
            f2 = fdot2(su[m + 16], wfuv[m + 16], f2);
            f3 = fdot2(su[m + 24], wfuv[m + 24], f3);
            g0 = fdot2(su[m],      wguv[m],      g0);
            g1 = fdot2(su[m + 8],  wguv[m + 8],  g1);
            g2 = fdot2(su[m + 16], wguv[m + 16], g2);
            g3 = fdot2(su[m + 24], wguv[m + 24], g3);
        }
        float f = sigmoid_fast(fh + (f0 + f1) + (f2 + f3));
        float g = tanh_fast(gh + bg_r + (g0 + g1) + (g2 + g3));
        h = fmaf(f, h - g, g);   // f*h + (1-f)*g

        // y_t — rotating wave, DPP reduce, LDS-buffered
        if (w == (t & 3)) {
            float y0 = wave_sum_dpp(h * wo0);
            float y1 = wave_sum_dpp(h * wo1);
            if (j == 63) {
                ybuf[2 * t]     = y0 + bo0;
                ybuf[2 * t + 1] = y1 + bo1;
            }
        }

        xsel = xsel_n;
    }

    // ---- flush y to global, coalesced float4 ----
    __syncthreads();
    {
        const float4* ys4 = reinterpret_cast<const float4*>(ybuf);
        float4*       yp4 = reinterpret_cast<float4*>(yp);
        for (int i = tid; i < TT * 2 / 4; i += 256) yp4[i] = ys4[i];
    }
}

extern "C" void kernel_launch(void* const* d_in, const int* in_sizes, int n_in,
                              void* d_out, int out_size, void* d_ws, size_t ws_size,
                              hipStream_t stream) {
    const float* x   = (const float*)d_in[0];
    const float* h0  = (const float*)d_in[1];
    const float* Wa  = (const float*)d_in[2];
    const float* ba  = (const float*)d_in[3];
    const float* Wp1 = (const float*)d_in[4];
    const float* bp1 = (const float*)d_in[5];
    const float* Wp2 = (const float*)d_in[6];
    const float* bp2 = (const float*)d_in[7];
    const float* Wf  = (const float*)d_in[8];
    const float* bf  = (const float*)d_in[9];
    const float* Wg  = (const float*)d_in[10];
    const float* bg  = (const float*)d_in[11];
    const float* Wo  = (const float*)d_in[12];
    const float* bo  = (const float*)d_in[13];
    float* out = (float*)d_out;

    pgjanet_kernel<<<dim3(BB), dim3(256), 0, stream>>>(
        x, h0, Wa, ba, Wp1, bp1, Wp2, bp2, Wf, bf, Wg, bg, Wo, bo, out);
}